// Round 4
// baseline (4154.153 us; speedup 1.0000x reference)
//
#include <hip/hip_runtime.h>
#include <hip/hip_bf16.h>

#define N_IN    262144
#define N_OUT   393216
#define M_PAIRS 262144
#define KK      27
#define CIN     32
#define COUT    64
#define BN_EPS  1e-5f

#define TOTAL_E      (KK * M_PAIRS)          // 7,077,888
#define ROWS_PER_BIN 128
#define NR           (N_OUT / ROWS_PER_BIN)  // 3072
#define NBINS        (NR * KK)               // 82944 = 81 * 1024

typedef unsigned int u32;
typedef float f32x4 __attribute__((ext_vector_type(4)));
typedef short s16x8 __attribute__((ext_vector_type(8)));

static __device__ __forceinline__ short f2bf(float f) {
    __hip_bfloat16 h = __float2bfloat16(f);
    return *reinterpret_cast<short*>(&h);
}

// ---------------- W convert: f32 [K][CIN][COUT] -> bf16 [K][COUT][CIN] ------
__global__ __launch_bounds__(256) void w_convert(
    const float* __restrict__ W, short* __restrict__ Wt)
{
    const int t = blockIdx.x * 256 + threadIdx.x;
    if (t >= KK * COUT * CIN) return;
    const int k    = t / (COUT * CIN);
    const int rem  = t % (COUT * CIN);
    const int co   = rem / CIN;
    const int ci   = rem % CIN;
    Wt[t] = f2bf(W[k * CIN * COUT + ci * COUT + co]);
}

// ---------------- data convert: f32 [N_IN][CIN] -> bf16 rows (64 B/row) ----
__global__ __launch_bounds__(256) void data_convert(
    const f32x4* __restrict__ in, s16x8* __restrict__ outp)
{
    const int t = blockIdx.x * 256 + threadIdx.x;   // one per 8 floats
    if (t >= N_IN * CIN / 8) return;
    const f32x4 x0 = in[2 * t];
    const f32x4 x1 = in[2 * t + 1];
    s16x8 o;
    o[0] = f2bf(x0[0]); o[1] = f2bf(x0[1]); o[2] = f2bf(x0[2]); o[3] = f2bf(x0[3]);
    o[4] = f2bf(x1[0]); o[5] = f2bf(x1[1]); o[6] = f2bf(x1[2]); o[7] = f2bf(x1[3]);
    outp[t] = o;
}

// ---------------- Phase A1: histogram over (range, k) bins ----------------
__global__ __launch_bounds__(256) void bin_count(
    const int4* __restrict__ out_idx4, u32* __restrict__ cnt)
{
    const int stride = gridDim.x * 256;
    for (int e4 = blockIdx.x * 256 + threadIdx.x; e4 < TOTAL_E / 4; e4 += stride) {
        const int k = e4 >> 16;              // e = 4*e4 ; k = e >> 18
        const int4 v = out_idx4[e4];
        atomicAdd(&cnt[(v.x >> 7) * KK + k], 1u);
        atomicAdd(&cnt[(v.y >> 7) * KK + k], 1u);
        atomicAdd(&cnt[(v.z >> 7) * KK + k], 1u);
        atomicAdd(&cnt[(v.w >> 7) * KK + k], 1u);
    }
}

// ---------------- Phase A2: hierarchical exclusive scan (82944 = 81*1024) --
__global__ __launch_bounds__(1024) void scan_part(
    const u32* __restrict__ cnt, u32* __restrict__ partial)
{
    __shared__ u32 sh[1024];
    sh[threadIdx.x] = cnt[blockIdx.x * 1024 + threadIdx.x];
    __syncthreads();
    for (int d = 512; d > 0; d >>= 1) {
        if (threadIdx.x < d) sh[threadIdx.x] += sh[threadIdx.x + d];
        __syncthreads();
    }
    if (threadIdx.x == 0) partial[blockIdx.x] = sh[0];
}

__global__ void scan_small(u32* __restrict__ partial)  // 1 thread: 81 entries
{
    u32 run = 0;
    for (int i = 0; i < NBINS / 1024; ++i) {
        const u32 v = partial[i];
        partial[i] = run;
        run += v;
    }
}

__global__ __launch_bounds__(1024) void scan_final(
    u32* __restrict__ cnt, u32* __restrict__ off, const u32* __restrict__ partial)
{
    __shared__ u32 sh[1024];
    const int t = threadIdx.x;
    const int i = blockIdx.x * 1024 + t;
    const u32 v = cnt[i];
    sh[t] = v;
    __syncthreads();
    for (int d = 1; d < 1024; d <<= 1) {
        const u32 add = (t >= d) ? sh[t - d] : 0u;
        __syncthreads();
        sh[t] += add;
        __syncthreads();
    }
    const u32 excl = sh[t] - v + partial[blockIdx.x];
    off[i] = excl;
    cnt[i] = excl;                 // cursor for A3
    if (blockIdx.x == 0 && t == 0) off[NBINS] = TOTAL_E;
}

// ---------------- Phase A3: scatter packed records into segments ----------
// record = in_i (18b) | local_out (7b) << 18
__global__ __launch_bounds__(256) void bin_scatter(
    const int4* __restrict__ in_idx4, const int4* __restrict__ out_idx4,
    u32* __restrict__ cursor, u32* __restrict__ rec)
{
    const int stride = gridDim.x * 256;
    for (int e4 = blockIdx.x * 256 + threadIdx.x; e4 < TOTAL_E / 4; e4 += stride) {
        const int k  = e4 >> 16;
        const int4 oi = out_idx4[e4];
        const int4 ii = in_idx4[e4];
        {
            const u32 pos = atomicAdd(&cursor[(oi.x >> 7) * KK + k], 1u);
            rec[pos] = (u32)ii.x | ((u32)(oi.x & 127) << 18);
        }
        {
            const u32 pos = atomicAdd(&cursor[(oi.y >> 7) * KK + k], 1u);
            rec[pos] = (u32)ii.y | ((u32)(oi.y & 127) << 18);
        }
        {
            const u32 pos = atomicAdd(&cursor[(oi.z >> 7) * KK + k], 1u);
            rec[pos] = (u32)ii.z | ((u32)(oi.z & 127) << 18);
        }
        {
            const u32 pos = atomicAdd(&cursor[(oi.w >> 7) * KK + k], 1u);
            rec[pos] = (u32)ii.w | ((u32)(oi.w & 127) << 18);
        }
    }
}

// ---------------- Phase B: MFMA per-range accumulate + fused BN stats ------
// Per wave per k-segment: batches of 128 records (8 sub-batches of 16).
// All rec loads + all gathers issued before first use -> ~8 gathers in flight.
// FMT 0: data pre-converted to bf16 rows (16B/lane). FMT 1: f32 rows.
template<int FMT>
__global__ __launch_bounds__(256) void range_accum_t(
    const void* __restrict__ datav,
    const short* __restrict__ Wt,     // [K, COUT, CIN] bf16 bits
    const u32*  __restrict__ off,     // [NBINS+1]
    const u32*  __restrict__ rec,     // [TOTAL_E + pad]
    float*      __restrict__ out,     // [N_OUT, COUT]
    float*      __restrict__ stats)   // [128]
{
    __shared__ float acc[ROWS_PER_BIN * COUT];  // 32 KB
    __shared__ float sred[512];

    const int r    = blockIdx.x;
    const int tid  = threadIdx.x;
    const int wave = tid >> 6;
    const int lane = tid & 63;
    const int jrow = lane & 15;      // A row / D col index
    const int kq   = lane >> 4;      // 0..3 : k-chunk / D row group

    const short* dbf = (const short*)datav;
    const float* df  = (const float*)datav;

    for (int i = tid; i < ROWS_PER_BIN * COUT; i += 256) acc[i] = 0.0f;
    __syncthreads();

    for (int k = wave; k < KK; k += 4) {
        const short* wb = Wt + (k * COUT + jrow) * CIN + kq * 8;
        const s16x8 b0 = *(const s16x8*)(wb + 0 * 16 * CIN);
        const s16x8 b1 = *(const s16x8*)(wb + 1 * 16 * CIN);
        const s16x8 b2 = *(const s16x8*)(wb + 2 * 16 * CIN);
        const s16x8 b3 = *(const s16x8*)(wb + 3 * 16 * CIN);

        const u32 begin = off[r * KK + k];
        const u32 end   = off[r * KK + k + 1];
        for (u32 base = begin; base < end; base += 128) {
            u32 rc[8];
            s16x8 a[8];
            // 1) all record loads (sequential, cheap)
            #pragma unroll
            for (int b = 0; b < 8; ++b) {
                u32 slot = base + (u32)(b * 16 + jrow);
                slot = slot < end ? slot : end - 1;    // clamp: dup row, cached
                rc[b] = rec[slot];
            }
            // 2) all gathers issued back-to-back -> MLP
            #pragma unroll
            for (int b = 0; b < 8; ++b) {
                const int in_i = (int)(rc[b] & 0x3FFFFu);
                if constexpr (FMT == 0) {
                    a[b] = *(const s16x8*)(dbf + (size_t)in_i * CIN + kq * 8);
                } else {
                    const float* dp = df + (size_t)in_i * CIN + kq * 8;
                    const f32x4 x0 = *(const f32x4*)dp;
                    const f32x4 x1 = *(const f32x4*)(dp + 4);
                    s16x8 t;
                    t[0] = f2bf(x0[0]); t[1] = f2bf(x0[1]); t[2] = f2bf(x0[2]); t[3] = f2bf(x0[3]);
                    t[4] = f2bf(x1[0]); t[5] = f2bf(x1[1]); t[6] = f2bf(x1[2]); t[7] = f2bf(x1[3]);
                    a[b] = t;
                }
            }
            // 3) zero A-rows of clamped (invalid) slots
            #pragma unroll
            for (int b = 0; b < 8; ++b) {
                if (base + (u32)(b * 16 + jrow) >= end)
                    a[b] = (s16x8){0, 0, 0, 0, 0, 0, 0, 0};
            }
            // 4) MFMA + LDS scatter per sub-batch
            #pragma unroll
            for (int b = 0; b < 8; ++b) {
                const f32x4 z = {0.f, 0.f, 0.f, 0.f};
                const f32x4 d0 = __builtin_amdgcn_mfma_f32_16x16x32_bf16(a[b], b0, z, 0, 0, 0);
                const f32x4 d1 = __builtin_amdgcn_mfma_f32_16x16x32_bf16(a[b], b1, z, 0, 0, 0);
                const f32x4 d2 = __builtin_amdgcn_mfma_f32_16x16x32_bf16(a[b], b2, z, 0, 0, 0);
                const f32x4 d3 = __builtin_amdgcn_mfma_f32_16x16x32_bf16(a[b], b3, z, 0, 0, 0);
                #pragma unroll
                for (int g = 0; g < 4; ++g) {
                    const u32 rr = (u32)__shfl((int)rc[b], kq * 4 + g, 64);
                    const int lo = (int)((rr >> 18) & 127u);
                    float* ap = acc + lo * COUT + jrow;
                    atomicAdd(ap + 0,  d0[g]);
                    atomicAdd(ap + 16, d1[g]);
                    atomicAdd(ap + 32, d2[g]);
                    atomicAdd(ap + 48, d3[g]);
                }
            }
        }
    }
    __syncthreads();

    // fused BN partial stats: thread t covers channel (t&63), rows (t>>6)::4
    {
        const int c = tid & 63;
        float s = 0.0f, sq = 0.0f;
        for (int row = tid >> 6; row < ROWS_PER_BIN; row += 4) {
            const float x = acc[row * COUT + c];
            s += x; sq += x * x;
        }
        sred[tid]       = s;
        sred[256 + tid] = sq;
        __syncthreads();
        if (tid < 64) {
            atomicAdd(&stats[tid],      sred[tid] + sred[tid + 64] + sred[tid + 128] + sred[tid + 192]);
            atomicAdd(&stats[64 + tid], sred[256 + tid] + sred[320 + tid] + sred[384 + tid] + sred[448 + tid]);
        }
    }

    // coalesced float4 store of the 128x64 block
    const float4* a4 = (const float4*)acc;
    float4* o4 = (float4*)out;
    for (int i = tid; i < ROWS_PER_BIN * COUT / 4; i += 256)
        o4[r * (ROWS_PER_BIN * COUT / 4) + i] = a4[i];
}

// ---------------- BN normalize (in place) ----------------
__global__ __launch_bounds__(256) void bn_norm(
    float* __restrict__ out, const float* __restrict__ stats,
    const float* __restrict__ gamma, const float* __restrict__ beta)
{
    __shared__ float scale[COUT], bias[COUT];
    if (threadIdx.x < COUT) {
        const int c = threadIdx.x;
        const float invN = 1.0f / (float)N_OUT;
        const float mean = stats[c] * invN;
        const float var  = stats[64 + c] * invN - mean * mean;
        const float inv  = rsqrtf(var + BN_EPS);
        const float g    = gamma[c];
        scale[c] = inv * g;
        bias[c]  = beta[c] - mean * inv * g;
    }
    __syncthreads();

    const int tid    = blockIdx.x * blockDim.x + threadIdx.x;
    const int stride = gridDim.x * blockDim.x;
    const int total4 = N_OUT * COUT / 4;
    float4* o4 = (float4*)out;
    for (int i = tid; i < total4; i += stride) {
        float4 v = o4[i];
        const int c0 = (i * 4) & 63;
        v.x = v.x * scale[c0 + 0] + bias[c0 + 0];
        v.y = v.y * scale[c0 + 1] + bias[c0 + 1];
        v.z = v.z * scale[c0 + 2] + bias[c0 + 2];
        v.w = v.w * scale[c0 + 3] + bias[c0 + 3];
        o4[i] = v;
    }
}

// ---------------- Fallback (round-1 path) if workspace too small ----------
__global__ __launch_bounds__(256) void conv_scatter_fb(
    const float* __restrict__ data, const float* __restrict__ W,
    const int* __restrict__ in_idx, const int* __restrict__ out_idx,
    float* __restrict__ out)
{
    __shared__ float Wlds[CIN * COUT];
    const int k   = blockIdx.x / 256;
    const int blk = blockIdx.x % 256;
    for (int i = threadIdx.x; i < CIN * COUT; i += 256)
        Wlds[i] = W[k * CIN * COUT + i];
    __syncthreads();
    const int wave = threadIdx.x >> 6;
    const int lane = threadIdx.x & 63;
    const int base = k * M_PAIRS + blk * 1024 + wave * 256;
    for (int p = 0; p < 256; ++p) {
        const int in_i  = in_idx[base + p];
        const int out_i = out_idx[base + p];
        const float val = data[in_i * CIN + (lane & 31)];
        float a = 0.0f;
        #pragma unroll
        for (int c = 0; c < CIN; ++c)
            a = fmaf(__shfl(val, c, 64), Wlds[c * COUT + lane], a);
        atomicAdd(&out[out_i * COUT + lane], a);
    }
}

__global__ __launch_bounds__(256) void bn_stats_fb(
    const float* __restrict__ out, float* __restrict__ stats)
{
    const int tid    = blockIdx.x * 256 + threadIdx.x;
    const int stride = gridDim.x * 256;
    float s = 0.0f, sq = 0.0f;
    for (int i = tid; i < N_OUT * COUT; i += stride) {
        const float x = out[i]; s += x; sq += x * x;
    }
    __shared__ float ls[256], lsq[256];
    ls[threadIdx.x] = s; lsq[threadIdx.x] = sq;
    __syncthreads();
    if (threadIdx.x < 64) {
        const int c = threadIdx.x;
        atomicAdd(&stats[c],      ls[c] + ls[c+64] + ls[c+128] + ls[c+192]);
        atomicAdd(&stats[64 + c], lsq[c] + lsq[c+64] + lsq[c+128] + lsq[c+192]);
    }
}

extern "C" void kernel_launch(void* const* d_in, const int* in_sizes, int n_in,
                              void* d_out, int out_size, void* d_ws, size_t ws_size,
                              hipStream_t stream) {
    const float* data    = (const float*)d_in[0];
    const float* W       = (const float*)d_in[1];
    const float* gamma   = (const float*)d_in[2];
    const float* beta    = (const float*)d_in[3];
    const int*   in_idx  = (const int*)d_in[4];
    const int*   out_idx = (const int*)d_in[5];
    float* out = (float*)d_out;

    // workspace layout (u32 units; every section 16B-aligned)
    u32* cnt     = (u32*)d_ws;                       // NBINS
    u32* off     = cnt + NBINS;                      // NBINS+4
    u32* rec     = off + NBINS + 4;                  // TOTAL_E + 16
    u32* partial = rec + TOTAL_E + 16;               // 128
    short* Wt    = (short*)(partial + 128);          // KK*COUT*CIN shorts
    float* stats = (float*)(Wt + KK * COUT * CIN);   // 128
    short* dataBF = (short*)(stats + 128);           // N_IN*CIN shorts (16.8 MB)

    const size_t base_needed =
        (size_t)(NBINS + NBINS + 4 + TOTAL_E + 16 + 128 + KK * COUT * CIN / 2 + 128) * 4;
    const size_t bf_needed = base_needed + (size_t)N_IN * CIN * 2;

    if (ws_size >= base_needed) {
        hipMemsetAsync(cnt, 0, (size_t)NBINS * sizeof(u32), stream);
        hipMemsetAsync(stats, 0, 128 * sizeof(float), stream);

        w_convert<<<(KK * COUT * CIN + 255) / 256, 256, 0, stream>>>(W, Wt);
        bin_count<<<2048, 256, 0, stream>>>((const int4*)out_idx, cnt);
        scan_part<<<NBINS / 1024, 1024, 0, stream>>>(cnt, partial);
        scan_small<<<1, 1, 0, stream>>>(partial);
        scan_final<<<NBINS / 1024, 1024, 0, stream>>>(cnt, off, partial);
        bin_scatter<<<2048, 256, 0, stream>>>((const int4*)in_idx, (const int4*)out_idx, cnt, rec);

        if (ws_size >= bf_needed) {
            data_convert<<<(N_IN * CIN / 8 + 255) / 256, 256, 0, stream>>>(
                (const f32x4*)data, (s16x8*)dataBF);
            range_accum_t<0><<<NR, 256, 0, stream>>>(dataBF, Wt, off, rec, out, stats);
        } else {
            range_accum_t<1><<<NR, 256, 0, stream>>>(data, Wt, off, rec, out, stats);
        }
        bn_norm<<<2048, 256, 0, stream>>>(out, stats, gamma, beta);
    } else {
        float* stats_fb = (float*)d_ws;
        hipMemsetAsync(d_out, 0, (size_t)N_OUT * COUT * sizeof(float), stream);
        hipMemsetAsync(stats_fb, 0, 128 * sizeof(float), stream);
        conv_scatter_fb<<<KK * 256, 256, 0, stream>>>(data, W, in_idx, out_idx, out);
        bn_stats_fb<<<1024, 256, 0, stream>>>(out, stats_fb);
        bn_norm<<<2048, 256, 0, stream>>>(out, stats_fb, gamma, beta);
    }
}

// Round 5
// 3262.015 us; speedup vs baseline: 1.2735x; 1.2735x over previous
//
#include <hip/hip_runtime.h>
#include <hip/hip_bf16.h>

#define N_IN    262144
#define N_OUT   393216
#define M_PAIRS 262144
#define KK      27
#define CIN     32
#define COUT    64
#define BN_EPS  1e-5f

#define TOTAL_E      (KK * M_PAIRS)          // 7,077,888
#define ROWS_PER_BIN 128
#define NR           (N_OUT / ROWS_PER_BIN)  // 3072
#define NBINS        (NR * KK)               // 82944 = 81 * 1024

typedef unsigned int u32;
typedef float f32x4 __attribute__((ext_vector_type(4)));
typedef short s16x8 __attribute__((ext_vector_type(8)));

static __device__ __forceinline__ short f2bf(float f) {
    __hip_bfloat16 h = __float2bfloat16(f);
    return *reinterpret_cast<short*>(&h);
}

// ---------------- W convert: f32 [K][CIN][COUT] -> bf16 [K][COUT][CIN] ------
__global__ __launch_bounds__(256) void w_convert(
    const float* __restrict__ W, short* __restrict__ Wt)
{
    const int t = blockIdx.x * 256 + threadIdx.x;
    if (t >= KK * COUT * CIN) return;
    const int k    = t / (COUT * CIN);
    const int rem  = t % (COUT * CIN);
    const int co   = rem / CIN;
    const int ci   = rem % CIN;
    Wt[t] = f2bf(W[k * CIN * COUT + ci * COUT + co]);
}

// ---------------- data convert: f32 [N_IN][CIN] -> bf16 rows (64 B/row) ----
__global__ __launch_bounds__(256) void data_convert(
    const f32x4* __restrict__ in, s16x8* __restrict__ outp)
{
    const int t = blockIdx.x * 256 + threadIdx.x;   // one per 8 floats
    if (t >= N_IN * CIN / 8) return;
    const f32x4 x0 = in[2 * t];
    const f32x4 x1 = in[2 * t + 1];
    s16x8 o;
    o[0] = f2bf(x0[0]); o[1] = f2bf(x0[1]); o[2] = f2bf(x0[2]); o[3] = f2bf(x0[3]);
    o[4] = f2bf(x1[0]); o[5] = f2bf(x1[1]); o[6] = f2bf(x1[2]); o[7] = f2bf(x1[3]);
    outp[t] = o;
}

// ---------------- Phase A1: histogram over (range, k) bins ----------------
__global__ __launch_bounds__(256) void bin_count(
    const int4* __restrict__ out_idx4, u32* __restrict__ cnt)
{
    const int stride = gridDim.x * 256;
    for (int e4 = blockIdx.x * 256 + threadIdx.x; e4 < TOTAL_E / 4; e4 += stride) {
        const int k = e4 >> 16;              // e = 4*e4 ; k = e >> 18
        const int4 v = out_idx4[e4];
        atomicAdd(&cnt[(v.x >> 7) * KK + k], 1u);
        atomicAdd(&cnt[(v.y >> 7) * KK + k], 1u);
        atomicAdd(&cnt[(v.z >> 7) * KK + k], 1u);
        atomicAdd(&cnt[(v.w >> 7) * KK + k], 1u);
    }
}

// ---------------- Phase A2: hierarchical exclusive scan (82944 = 81*1024) --
__global__ __launch_bounds__(1024) void scan_part(
    const u32* __restrict__ cnt, u32* __restrict__ partial)
{
    __shared__ u32 sh[1024];
    sh[threadIdx.x] = cnt[blockIdx.x * 1024 + threadIdx.x];
    __syncthreads();
    for (int d = 512; d > 0; d >>= 1) {
        if (threadIdx.x < d) sh[threadIdx.x] += sh[threadIdx.x + d];
        __syncthreads();
    }
    if (threadIdx.x == 0) partial[blockIdx.x] = sh[0];
}

__global__ void scan_small(u32* __restrict__ partial)  // 1 thread: 81 entries
{
    u32 run = 0;
    for (int i = 0; i < NBINS / 1024; ++i) {
        const u32 v = partial[i];
        partial[i] = run;
        run += v;
    }
}

__global__ __launch_bounds__(1024) void scan_final(
    u32* __restrict__ cnt, u32* __restrict__ off, const u32* __restrict__ partial)
{
    __shared__ u32 sh[1024];
    const int t = threadIdx.x;
    const int i = blockIdx.x * 1024 + t;
    const u32 v = cnt[i];
    sh[t] = v;
    __syncthreads();
    for (int d = 1; d < 1024; d <<= 1) {
        const u32 add = (t >= d) ? sh[t - d] : 0u;
        __syncthreads();
        sh[t] += add;
        __syncthreads();
    }
    const u32 excl = sh[t] - v + partial[blockIdx.x];
    off[i] = excl;
    cnt[i] = excl;                 // cursor for A3
    if (blockIdx.x == 0 && t == 0) off[NBINS] = TOTAL_E;
}

// ---------------- Phase A3: scatter packed records into segments ----------
// record = in_i (18b) | local_out (7b) << 18
__global__ __launch_bounds__(256) void bin_scatter(
    const int4* __restrict__ in_idx4, const int4* __restrict__ out_idx4,
    u32* __restrict__ cursor, u32* __restrict__ rec)
{
    const int stride = gridDim.x * 256;
    for (int e4 = blockIdx.x * 256 + threadIdx.x; e4 < TOTAL_E / 4; e4 += stride) {
        const int k  = e4 >> 16;
        const int4 oi = out_idx4[e4];
        const int4 ii = in_idx4[e4];
        {
            const u32 pos = atomicAdd(&cursor[(oi.x >> 7) * KK + k], 1u);
            rec[pos] = (u32)ii.x | ((u32)(oi.x & 127) << 18);
        }
        {
            const u32 pos = atomicAdd(&cursor[(oi.y >> 7) * KK + k], 1u);
            rec[pos] = (u32)ii.y | ((u32)(oi.y & 127) << 18);
        }
        {
            const u32 pos = atomicAdd(&cursor[(oi.z >> 7) * KK + k], 1u);
            rec[pos] = (u32)ii.z | ((u32)(oi.z & 127) << 18);
        }
        {
            const u32 pos = atomicAdd(&cursor[(oi.w >> 7) * KK + k], 1u);
            rec[pos] = (u32)ii.w | ((u32)(oi.w & 127) << 18);
        }
    }
}

// ---------------- Phase B: MFMA per-range accumulate + fused BN stats ------
// Per wave per k-segment: batches of 128 records = 8 sub-batches of 16.
// Named registers + sched_barrier keep all 8 gathers in flight (MLP).
__global__ __launch_bounds__(256, 4) void range_accum(
    const short* __restrict__ dbf,    // [N_IN, CIN] bf16 bits
    const short* __restrict__ Wt,     // [K, COUT, CIN] bf16 bits
    const u32*  __restrict__ off,     // [NBINS+1]
    const u32*  __restrict__ rec,     // [TOTAL_E + pad]
    float*      __restrict__ out,     // [N_OUT, COUT]
    float*      __restrict__ stats)   // [128]
{
    __shared__ float acc[ROWS_PER_BIN * COUT];  // 32 KB
    __shared__ float sred[512];

    const int r    = blockIdx.x;
    const int tid  = threadIdx.x;
    const int wave = tid >> 6;
    const int lane = tid & 63;
    const int jrow = lane & 15;      // A row / D col index
    const int kq   = lane >> 4;      // 0..3 : k-chunk / D row group

    // all 28 segment boundaries for this range, one per lane
    const u32 offv = off[r * KK + (lane < KK + 1 ? lane : KK)];

    for (int i = tid; i < ROWS_PER_BIN * COUT; i += 256) acc[i] = 0.0f;
    __syncthreads();

    for (int k = wave; k < KK; k += 4) {
        const short* wb = Wt + (k * COUT + jrow) * CIN + kq * 8;
        const s16x8 b0 = *(const s16x8*)(wb + 0 * 16 * CIN);
        const s16x8 b1 = *(const s16x8*)(wb + 1 * 16 * CIN);
        const s16x8 b2 = *(const s16x8*)(wb + 2 * 16 * CIN);
        const s16x8 b3 = *(const s16x8*)(wb + 3 * 16 * CIN);

        const u32 begin = (u32)__shfl((int)offv, k, 64);
        const u32 end   = (u32)__shfl((int)offv, k + 1, 64);

        for (u32 base = begin; base < end; base += 128) {
            const u32 len = end - base;          // wave-uniform
            u32 rc0, rc1, rc2, rc3, rc4, rc5, rc6, rc7;
            s16x8 a0, a1, a2, a3, a4, a5, a6, a7;

            // ---- record loads (clustered) ----
#define LOADREC(b, rcv)  if (b * 16 < len) { \
                u32 s = base + b * 16 + (u32)jrow; \
                s = s < end ? s : end - 1; \
                rcv = rec[s]; }
            LOADREC(0, rc0) LOADREC(1, rc1) LOADREC(2, rc2) LOADREC(3, rc3)
            LOADREC(4, rc4) LOADREC(5, rc5) LOADREC(6, rc6) LOADREC(7, rc7)
#undef LOADREC

            // ---- gathers (clustered; 8 independent dwordx4 in flight) ----
#define GATHER(b, rcv, av)  if (b * 16 < len) { \
                av = *(const s16x8*)(dbf + (size_t)(rcv & 0x3FFFFu) * CIN + kq * 8); }
            GATHER(0, rc0, a0) GATHER(1, rc1, a1) GATHER(2, rc2, a2) GATHER(3, rc3, a3)
            GATHER(4, rc4, a4) GATHER(5, rc5, a5) GATHER(6, rc6, a6) GATHER(7, rc7, a7)
#undef GATHER

            // keep the load cluster above the use cluster
            __builtin_amdgcn_sched_barrier(0);

            // ---- zero invalid rows, MFMA, LDS scatter ----
#define PROC(b, rcv, av)  if (b * 16 < len) { \
                if (b * 16 + (u32)jrow >= len) \
                    av = (s16x8){0, 0, 0, 0, 0, 0, 0, 0}; \
                const f32x4 z = {0.f, 0.f, 0.f, 0.f}; \
                const f32x4 d0 = __builtin_amdgcn_mfma_f32_16x16x32_bf16(av, b0, z, 0, 0, 0); \
                const f32x4 d1 = __builtin_amdgcn_mfma_f32_16x16x32_bf16(av, b1, z, 0, 0, 0); \
                const f32x4 d2 = __builtin_amdgcn_mfma_f32_16x16x32_bf16(av, b2, z, 0, 0, 0); \
                const f32x4 d3 = __builtin_amdgcn_mfma_f32_16x16x32_bf16(av, b3, z, 0, 0, 0); \
                _Pragma("unroll") \
                for (int g = 0; g < 4; ++g) { \
                    const u32 rr = (u32)__shfl((int)rcv, kq * 4 + g, 64); \
                    const int lo = (int)((rr >> 18) & 127u); \
                    float* ap = acc + lo * COUT + jrow; \
                    atomicAdd(ap + 0,  d0[g]); \
                    atomicAdd(ap + 16, d1[g]); \
                    atomicAdd(ap + 32, d2[g]); \
                    atomicAdd(ap + 48, d3[g]); \
                } }
            PROC(0, rc0, a0) PROC(1, rc1, a1) PROC(2, rc2, a2) PROC(3, rc3, a3)
            PROC(4, rc4, a4) PROC(5, rc5, a5) PROC(6, rc6, a6) PROC(7, rc7, a7)
#undef PROC
        }
    }
    __syncthreads();

    // fused BN partial stats: thread t covers channel (t&63), rows (t>>6)::4
    {
        const int c = tid & 63;
        float s = 0.0f, sq = 0.0f;
        for (int row = tid >> 6; row < ROWS_PER_BIN; row += 4) {
            const float x = acc[row * COUT + c];
            s += x; sq += x * x;
        }
        sred[tid]       = s;
        sred[256 + tid] = sq;
        __syncthreads();
        if (tid < 64) {
            atomicAdd(&stats[tid],      sred[tid] + sred[tid + 64] + sred[tid + 128] + sred[tid + 192]);
            atomicAdd(&stats[64 + tid], sred[256 + tid] + sred[320 + tid] + sred[384 + tid] + sred[448 + tid]);
        }
    }

    // coalesced float4 store of the 128x64 block
    const float4* a4p = (const float4*)acc;
    float4* o4 = (float4*)out;
    for (int i = tid; i < ROWS_PER_BIN * COUT / 4; i += 256)
        o4[r * (ROWS_PER_BIN * COUT / 4) + i] = a4p[i];
}

// ---------------- f32-data variant (no bf16 table in ws) ------------------
__global__ __launch_bounds__(256) void range_accum_f32(
    const float* __restrict__ df,
    const short* __restrict__ Wt,
    const u32*  __restrict__ off,
    const u32*  __restrict__ rec,
    float*      __restrict__ out,
    float*      __restrict__ stats)
{
    __shared__ float acc[ROWS_PER_BIN * COUT];
    __shared__ float sred[512];
    const int r    = blockIdx.x;
    const int tid  = threadIdx.x;
    const int wave = tid >> 6;
    const int lane = tid & 63;
    const int jrow = lane & 15;
    const int kq   = lane >> 4;

    for (int i = tid; i < ROWS_PER_BIN * COUT; i += 256) acc[i] = 0.0f;
    __syncthreads();

    for (int k = wave; k < KK; k += 4) {
        const short* wb = Wt + (k * COUT + jrow) * CIN + kq * 8;
        const s16x8 b0 = *(const s16x8*)(wb + 0 * 16 * CIN);
        const s16x8 b1 = *(const s16x8*)(wb + 1 * 16 * CIN);
        const s16x8 b2 = *(const s16x8*)(wb + 2 * 16 * CIN);
        const s16x8 b3 = *(const s16x8*)(wb + 3 * 16 * CIN);
        const u32 begin = off[r * KK + k];
        const u32 end   = off[r * KK + k + 1];
        for (u32 base = begin; base < end; base += 16) {
            u32 slot = base + (u32)jrow;
            const bool valid = slot < end;
            slot = valid ? slot : end - 1;
            const u32 rc = rec[slot];
            const float* dp = df + (size_t)(rc & 0x3FFFFu) * CIN + kq * 8;
            f32x4 x0 = *(const f32x4*)dp;
            f32x4 x1 = *(const f32x4*)(dp + 4);
            if (!valid) { x0 = (f32x4){0,0,0,0}; x1 = (f32x4){0,0,0,0}; }
            s16x8 a;
            a[0]=f2bf(x0[0]); a[1]=f2bf(x0[1]); a[2]=f2bf(x0[2]); a[3]=f2bf(x0[3]);
            a[4]=f2bf(x1[0]); a[5]=f2bf(x1[1]); a[6]=f2bf(x1[2]); a[7]=f2bf(x1[3]);
            const f32x4 z = {0.f,0.f,0.f,0.f};
            const f32x4 d0 = __builtin_amdgcn_mfma_f32_16x16x32_bf16(a, b0, z, 0, 0, 0);
            const f32x4 d1 = __builtin_amdgcn_mfma_f32_16x16x32_bf16(a, b1, z, 0, 0, 0);
            const f32x4 d2 = __builtin_amdgcn_mfma_f32_16x16x32_bf16(a, b2, z, 0, 0, 0);
            const f32x4 d3 = __builtin_amdgcn_mfma_f32_16x16x32_bf16(a, b3, z, 0, 0, 0);
            #pragma unroll
            for (int g = 0; g < 4; ++g) {
                const u32 rr = (u32)__shfl((int)rc, kq * 4 + g, 64);
                const int lo = (int)((rr >> 18) & 127u);
                float* ap = acc + lo * COUT + jrow;
                atomicAdd(ap + 0,  d0[g]);
                atomicAdd(ap + 16, d1[g]);
                atomicAdd(ap + 32, d2[g]);
                atomicAdd(ap + 48, d3[g]);
            }
        }
    }
    __syncthreads();
    {
        const int c = tid & 63;
        float s = 0.0f, sq = 0.0f;
        for (int row = tid >> 6; row < ROWS_PER_BIN; row += 4) {
            const float x = acc[row * COUT + c];
            s += x; sq += x * x;
        }
        sred[tid] = s; sred[256 + tid] = sq;
        __syncthreads();
        if (tid < 64) {
            atomicAdd(&stats[tid],      sred[tid] + sred[tid+64] + sred[tid+128] + sred[tid+192]);
            atomicAdd(&stats[64+tid],   sred[256+tid] + sred[320+tid] + sred[384+tid] + sred[448+tid]);
        }
    }
    const float4* a4p = (const float4*)acc;
    float4* o4 = (float4*)out;
    for (int i = tid; i < ROWS_PER_BIN * COUT / 4; i += 256)
        o4[r * (ROWS_PER_BIN * COUT / 4) + i] = a4p[i];
}

// ---------------- BN normalize (in place) ----------------
__global__ __launch_bounds__(256) void bn_norm(
    float* __restrict__ out, const float* __restrict__ stats,
    const float* __restrict__ gamma, const float* __restrict__ beta)
{
    __shared__ float scale[COUT], bias[COUT];
    if (threadIdx.x < COUT) {
        const int c = threadIdx.x;
        const float invN = 1.0f / (float)N_OUT;
        const float mean = stats[c] * invN;
        const float var  = stats[64 + c] * invN - mean * mean;
        const float inv  = rsqrtf(var + BN_EPS);
        const float g    = gamma[c];
        scale[c] = inv * g;
        bias[c]  = beta[c] - mean * inv * g;
    }
    __syncthreads();

    const int tid    = blockIdx.x * blockDim.x + threadIdx.x;
    const int stride = gridDim.x * blockDim.x;
    const int total4 = N_OUT * COUT / 4;
    float4* o4 = (float4*)out;
    for (int i = tid; i < total4; i += stride) {
        float4 v = o4[i];
        const int c0 = (i * 4) & 63;
        v.x = v.x * scale[c0 + 0] + bias[c0 + 0];
        v.y = v.y * scale[c0 + 1] + bias[c0 + 1];
        v.z = v.z * scale[c0 + 2] + bias[c0 + 2];
        v.w = v.w * scale[c0 + 3] + bias[c0 + 3];
        o4[i] = v;
    }
}

// ---------------- Fallback (round-1 path) if workspace too small ----------
__global__ __launch_bounds__(256) void conv_scatter_fb(
    const float* __restrict__ data, const float* __restrict__ W,
    const int* __restrict__ in_idx, const int* __restrict__ out_idx,
    float* __restrict__ out)
{
    __shared__ float Wlds[CIN * COUT];
    const int k   = blockIdx.x / 256;
    const int blk = blockIdx.x % 256;
    for (int i = threadIdx.x; i < CIN * COUT; i += 256)
        Wlds[i] = W[k * CIN * COUT + i];
    __syncthreads();
    const int wave = threadIdx.x >> 6;
    const int lane = threadIdx.x & 63;
    const int base = k * M_PAIRS + blk * 1024 + wave * 256;
    for (int p = 0; p < 256; ++p) {
        const int in_i  = in_idx[base + p];
        const int out_i = out_idx[base + p];
        const float val = data[in_i * CIN + (lane & 31)];
        float a = 0.0f;
        #pragma unroll
        for (int c = 0; c < CIN; ++c)
            a = fmaf(__shfl(val, c, 64), Wlds[c * COUT + lane], a);
        atomicAdd(&out[out_i * COUT + lane], a);
    }
}

__global__ __launch_bounds__(256) void bn_stats_fb(
    const float* __restrict__ out, float* __restrict__ stats)
{
    const int tid    = blockIdx.x * 256 + threadIdx.x;
    const int stride = gridDim.x * 256;
    float s = 0.0f, sq = 0.0f;
    for (int i = tid; i < N_OUT * COUT; i += stride) {
        const float x = out[i]; s += x; sq += x * x;
    }
    __shared__ float ls[256], lsq[256];
    ls[threadIdx.x] = s; lsq[threadIdx.x] = sq;
    __syncthreads();
    if (threadIdx.x < 64) {
        const int c = threadIdx.x;
        atomicAdd(&stats[c],      ls[c] + ls[c+64] + ls[c+128] + ls[c+192]);
        atomicAdd(&stats[64 + c], lsq[c] + lsq[c+64] + lsq[c+128] + lsq[c+192]);
    }
}

extern "C" void kernel_launch(void* const* d_in, const int* in_sizes, int n_in,
                              void* d_out, int out_size, void* d_ws, size_t ws_size,
                              hipStream_t stream) {
    const float* data    = (const float*)d_in[0];
    const float* W       = (const float*)d_in[1];
    const float* gamma   = (const float*)d_in[2];
    const float* beta    = (const float*)d_in[3];
    const int*   in_idx  = (const int*)d_in[4];
    const int*   out_idx = (const int*)d_in[5];
    float* out = (float*)d_out;

    // workspace layout (u32 units; every section 16B-aligned)
    u32* cnt     = (u32*)d_ws;                       // NBINS
    u32* off     = cnt + NBINS;                      // NBINS+4
    u32* rec     = off + NBINS + 4;                  // TOTAL_E + 16
    u32* partial = rec + TOTAL_E + 16;               // 128
    short* Wt    = (short*)(partial + 128);          // KK*COUT*CIN shorts
    float* stats = (float*)(Wt + KK * COUT * CIN);   // 128
    short* dataBF = (short*)(stats + 128);           // N_IN*CIN shorts (16.8 MB)

    const size_t base_needed =
        (size_t)(NBINS + NBINS + 4 + TOTAL_E + 16 + 128 + KK * COUT * CIN / 2 + 128) * 4;
    const size_t bf_needed = base_needed + (size_t)N_IN * CIN * 2;

    if (ws_size >= base_needed) {
        hipMemsetAsync(cnt, 0, (size_t)NBINS * sizeof(u32), stream);
        hipMemsetAsync(stats, 0, 128 * sizeof(float), stream);

        w_convert<<<(KK * COUT * CIN + 255) / 256, 256, 0, stream>>>(W, Wt);
        bin_count<<<2048, 256, 0, stream>>>((const int4*)out_idx, cnt);
        scan_part<<<NBINS / 1024, 1024, 0, stream>>>(cnt, partial);
        scan_small<<<1, 1, 0, stream>>>(partial);
        scan_final<<<NBINS / 1024, 1024, 0, stream>>>(cnt, off, partial);
        bin_scatter<<<2048, 256, 0, stream>>>((const int4*)in_idx, (const int4*)out_idx, cnt, rec);

        if (ws_size >= bf_needed) {
            data_convert<<<(N_IN * CIN / 8 + 255) / 256, 256, 0, stream>>>(
                (const f32x4*)data, (s16x8*)dataBF);
            range_accum<<<NR, 256, 0, stream>>>(dataBF, Wt, off, rec, out, stats);
        } else {
            range_accum_f32<<<NR, 256, 0, stream>>>(data, Wt, off, rec, out, stats);
        }
        bn_norm<<<2048, 256, 0, stream>>>(out, stats, gamma, beta);
    } else {
        float* stats_fb = (float*)d_ws;
        hipMemsetAsync(d_out, 0, (size_t)N_OUT * COUT * sizeof(float), stream);
        hipMemsetAsync(stats_fb, 0, 128 * sizeof(float), stream);
        conv_scatter_fb<<<KK * 256, 256, 0, stream>>>(data, W, in_idx, out_idx, out);
        bn_stats_fb<<<1024, 256, 0, stream>>>(out, stats_fb);
        bn_norm<<<2048, 256, 0, stream>>>(out, stats_fb, gamma, beta);
    }
}

// Round 6
// 3210.214 us; speedup vs baseline: 1.2940x; 1.0161x over previous
//
#include <hip/hip_runtime.h>
#include <hip/hip_bf16.h>

#define N_IN    262144
#define N_OUT   393216
#define M_PAIRS 262144
#define KK      27
#define CIN     32
#define COUT    64
#define BN_EPS  1e-5f

#define TOTAL_E      (KK * M_PAIRS)          // 7,077,888
#define ROWS_PER_BIN 128
#define NR           (N_OUT / ROWS_PER_BIN)  // 3072
#define NBINS        (NR * KK)               // 82944 = 81 * 1024
#define ACCW         65                      // padded acc row stride (bank spread)

typedef unsigned int u32;
typedef float f32x4 __attribute__((ext_vector_type(4)));
typedef short s16x8 __attribute__((ext_vector_type(8)));

static __device__ __forceinline__ short f2bf(float f) {
    __hip_bfloat16 h = __float2bfloat16(f);
    return *reinterpret_cast<short*>(&h);
}

// ---------------- W convert: f32 [K][CIN][COUT] -> bf16 [K][COUT][CIN] ------
__global__ __launch_bounds__(256) void w_convert(
    const float* __restrict__ W, short* __restrict__ Wt)
{
    const int t = blockIdx.x * 256 + threadIdx.x;
    if (t >= KK * COUT * CIN) return;
    const int k    = t / (COUT * CIN);
    const int rem  = t % (COUT * CIN);
    const int co   = rem / CIN;
    const int ci   = rem % CIN;
    Wt[t] = f2bf(W[k * CIN * COUT + ci * COUT + co]);
}

// ---------------- data convert: f32 [N_IN][CIN] -> bf16 rows (64 B/row) ----
__global__ __launch_bounds__(256) void data_convert(
    const f32x4* __restrict__ in, s16x8* __restrict__ outp)
{
    const int t = blockIdx.x * 256 + threadIdx.x;   // one per 8 floats
    if (t >= N_IN * CIN / 8) return;
    const f32x4 x0 = in[2 * t];
    const f32x4 x1 = in[2 * t + 1];
    s16x8 o;
    o[0] = f2bf(x0[0]); o[1] = f2bf(x0[1]); o[2] = f2bf(x0[2]); o[3] = f2bf(x0[3]);
    o[4] = f2bf(x1[0]); o[5] = f2bf(x1[1]); o[6] = f2bf(x1[2]); o[7] = f2bf(x1[3]);
    outp[t] = o;
}

// ---------------- Phase A1: histogram over (range, k) bins ----------------
__global__ __launch_bounds__(256) void bin_count(
    const int4* __restrict__ out_idx4, u32* __restrict__ cnt)
{
    const int stride = gridDim.x * 256;
    for (int e4 = blockIdx.x * 256 + threadIdx.x; e4 < TOTAL_E / 4; e4 += stride) {
        const int k = e4 >> 16;              // e = 4*e4 ; k = e >> 18
        const int4 v = out_idx4[e4];
        atomicAdd(&cnt[(v.x >> 7) * KK + k], 1u);
        atomicAdd(&cnt[(v.y >> 7) * KK + k], 1u);
        atomicAdd(&cnt[(v.z >> 7) * KK + k], 1u);
        atomicAdd(&cnt[(v.w >> 7) * KK + k], 1u);
    }
}

// ---------------- Phase A2: hierarchical exclusive scan (82944 = 81*1024) --
__global__ __launch_bounds__(1024) void scan_part(
    const u32* __restrict__ cnt, u32* __restrict__ partial)
{
    __shared__ u32 sh[1024];
    sh[threadIdx.x] = cnt[blockIdx.x * 1024 + threadIdx.x];
    __syncthreads();
    for (int d = 512; d > 0; d >>= 1) {
        if (threadIdx.x < d) sh[threadIdx.x] += sh[threadIdx.x + d];
        __syncthreads();
    }
    if (threadIdx.x == 0) partial[blockIdx.x] = sh[0];
}

__global__ void scan_small(u32* __restrict__ partial)  // 1 thread: 81 entries
{
    u32 run = 0;
    for (int i = 0; i < NBINS / 1024; ++i) {
        const u32 v = partial[i];
        partial[i] = run;
        run += v;
    }
}

__global__ __launch_bounds__(1024) void scan_final(
    u32* __restrict__ cnt, u32* __restrict__ off, const u32* __restrict__ partial)
{
    __shared__ u32 sh[1024];
    const int t = threadIdx.x;
    const int i = blockIdx.x * 1024 + t;
    const u32 v = cnt[i];
    sh[t] = v;
    __syncthreads();
    for (int d = 1; d < 1024; d <<= 1) {
        const u32 add = (t >= d) ? sh[t - d] : 0u;
        __syncthreads();
        sh[t] += add;
        __syncthreads();
    }
    const u32 excl = sh[t] - v + partial[blockIdx.x];
    off[i] = excl;
    cnt[i] = excl;                 // cursor for A3
    if (blockIdx.x == 0 && t == 0) off[NBINS] = TOTAL_E;
}

// ---------------- Phase A3: scatter packed records into segments ----------
// record = in_i (18b) | local_out (7b) << 18
__global__ __launch_bounds__(256) void bin_scatter(
    const int4* __restrict__ in_idx4, const int4* __restrict__ out_idx4,
    u32* __restrict__ cursor, u32* __restrict__ rec)
{
    const int stride = gridDim.x * 256;
    for (int e4 = blockIdx.x * 256 + threadIdx.x; e4 < TOTAL_E / 4; e4 += stride) {
        const int k  = e4 >> 16;
        const int4 oi = out_idx4[e4];
        const int4 ii = in_idx4[e4];
        {
            const u32 pos = atomicAdd(&cursor[(oi.x >> 7) * KK + k], 1u);
            rec[pos] = (u32)ii.x | ((u32)(oi.x & 127) << 18);
        }
        {
            const u32 pos = atomicAdd(&cursor[(oi.y >> 7) * KK + k], 1u);
            rec[pos] = (u32)ii.y | ((u32)(oi.y & 127) << 18);
        }
        {
            const u32 pos = atomicAdd(&cursor[(oi.z >> 7) * KK + k], 1u);
            rec[pos] = (u32)ii.z | ((u32)(oi.z & 127) << 18);
        }
        {
            const u32 pos = atomicAdd(&cursor[(oi.w >> 7) * KK + k], 1u);
            rec[pos] = (u32)ii.w | ((u32)(oi.w & 127) << 18);
        }
    }
}

// ---------------- Phase B: swapped-operand MFMA accumulate ------------------
// mfma(A=W_tile, B=data_frag): D col = lane&15 = record -> scatter row index
// lo is LANE-LOCAL (no shfl). 8 waves; acc stride 65 spreads atomic banks.
__global__ __launch_bounds__(512, 6) void range_accum(
    const short* __restrict__ dbf,    // [N_IN, CIN] bf16 bits
    const short* __restrict__ Wt,     // [K, COUT, CIN] bf16 bits
    const u32*  __restrict__ off,     // [NBINS+1]
    const u32*  __restrict__ rec,     // [TOTAL_E + pad]
    float*      __restrict__ out,     // [N_OUT, COUT]
    float*      __restrict__ stats)   // [128]
{
    __shared__ float acc[ROWS_PER_BIN * ACCW];  // 33280 B
    __shared__ float sred[1024];                // 4 KB

    const int r    = blockIdx.x;
    const int tid  = threadIdx.x;
    const int wave = tid >> 6;       // 0..7
    const int lane = tid & 63;
    const int jrow = lane & 15;      // record slot within tile / D col
    const int kq   = lane >> 4;      // k-chunk of fragments / D row group

    for (int i = tid; i < ROWS_PER_BIN * ACCW; i += 512) acc[i] = 0.0f;
    __syncthreads();

    for (int k = wave; k < KK; k += 8) {
        // A-operand (W): lane jrow holds cout = t*16+jrow, cins kq*8..+7
        const short* wb = Wt + (k * COUT + jrow) * CIN + kq * 8;
        const s16x8 w0 = *(const s16x8*)(wb + 0 * 16 * CIN);
        const s16x8 w1 = *(const s16x8*)(wb + 1 * 16 * CIN);
        const s16x8 w2 = *(const s16x8*)(wb + 2 * 16 * CIN);
        const s16x8 w3 = *(const s16x8*)(wb + 3 * 16 * CIN);

        const u32 begin = off[r * KK + k];
        const u32 end   = off[r * KK + k + 1];

        for (u32 base = begin; base < end; base += 96) {
            const u32 len = end - base;          // wave-uniform
            u32 rc0 = 0, rc1 = 0, rc2 = 0, rc3 = 0, rc4 = 0, rc5 = 0;
            s16x8 a0, a1, a2, a3, a4, a5;

            // record loads (lane jrow's own record; pad covers over-read)
#define LOADREC(b, rcv)  if (b * 16 < len) { rcv = rec[base + b * 16 + (u32)jrow]; }
            LOADREC(0, rc0) LOADREC(1, rc1) LOADREC(2, rc2)
            LOADREC(3, rc3) LOADREC(4, rc4) LOADREC(5, rc5)
#undef LOADREC

            // gathers (B-operand: record jrow's data slice kq)
#define GATHER(b, rcv, av)  if (b * 16 < len) { \
                av = *(const s16x8*)(dbf + (size_t)(rcv & 0x3FFFFu) * CIN + kq * 8); }
            GATHER(0, rc0, a0) GATHER(1, rc1, a1) GATHER(2, rc2, a2)
            GATHER(3, rc3, a3) GATHER(4, rc4, a4) GATHER(5, rc5, a5)
#undef GATHER

            __builtin_amdgcn_sched_barrier(0);

            // MFMA (swapped operands) + lane-local LDS scatter
#define PROC(b, rcv, av)  if (b * 16 < len) { \
                if (b * 16 + (u32)jrow >= len) \
                    av = (s16x8){0, 0, 0, 0, 0, 0, 0, 0}; \
                const f32x4 z = {0.f, 0.f, 0.f, 0.f}; \
                const f32x4 d0 = __builtin_amdgcn_mfma_f32_16x16x32_bf16(w0, av, z, 0, 0, 0); \
                const f32x4 d1 = __builtin_amdgcn_mfma_f32_16x16x32_bf16(w1, av, z, 0, 0, 0); \
                const f32x4 d2 = __builtin_amdgcn_mfma_f32_16x16x32_bf16(w2, av, z, 0, 0, 0); \
                const f32x4 d3 = __builtin_amdgcn_mfma_f32_16x16x32_bf16(w3, av, z, 0, 0, 0); \
                const int lo = (int)((rcv >> 18) & 127u); \
                float* ap = acc + lo * ACCW + kq * 4; \
                _Pragma("unroll") \
                for (int g = 0; g < 4; ++g) { \
                    atomicAdd(ap + g,      d0[g]); \
                    atomicAdd(ap + 16 + g, d1[g]); \
                    atomicAdd(ap + 32 + g, d2[g]); \
                    atomicAdd(ap + 48 + g, d3[g]); \
                } }
            PROC(0, rc0, a0) PROC(1, rc1, a1) PROC(2, rc2, a2)
            PROC(3, rc3, a3) PROC(4, rc4, a4) PROC(5, rc5, a5)
#undef PROC
        }
    }
    __syncthreads();

    // fused BN partial stats: thread covers channel (tid&63), rows (tid>>6)::8
    {
        const int c = tid & 63;
        float s = 0.0f, sq = 0.0f;
        for (int row = tid >> 6; row < ROWS_PER_BIN; row += 8) {
            const float x = acc[row * ACCW + c];
            s += x; sq += x * x;
        }
        sred[tid]       = s;
        sred[512 + tid] = sq;
        __syncthreads();
        if (tid < 64) {
            float ts = 0.0f, tq = 0.0f;
            #pragma unroll
            for (int i = 0; i < 8; ++i) {
                ts += sred[tid + 64 * i];
                tq += sred[512 + tid + 64 * i];
            }
            atomicAdd(&stats[tid],      ts);
            atomicAdd(&stats[64 + tid], tq);
        }
    }

    // coalesced store of the 128x64 block (strip the ACCW pad)
    for (int i = tid; i < ROWS_PER_BIN * COUT; i += 512) {
        const int row = i >> 6;
        const int c   = i & 63;
        out[(size_t)r * (ROWS_PER_BIN * COUT) + i] = acc[row * ACCW + c];
    }
}

// ---------------- f32-data variant (no bf16 table in ws) ------------------
__global__ __launch_bounds__(256) void range_accum_f32(
    const float* __restrict__ df,
    const short* __restrict__ Wt,
    const u32*  __restrict__ off,
    const u32*  __restrict__ rec,
    float*      __restrict__ out,
    float*      __restrict__ stats)
{
    __shared__ float acc[ROWS_PER_BIN * COUT];
    __shared__ float sred[512];
    const int r    = blockIdx.x;
    const int tid  = threadIdx.x;
    const int wave = tid >> 6;
    const int lane = tid & 63;
    const int jrow = lane & 15;
    const int kq   = lane >> 4;

    for (int i = tid; i < ROWS_PER_BIN * COUT; i += 256) acc[i] = 0.0f;
    __syncthreads();

    for (int k = wave; k < KK; k += 4) {
        const short* wb = Wt + (k * COUT + jrow) * CIN + kq * 8;
        const s16x8 b0 = *(const s16x8*)(wb + 0 * 16 * CIN);
        const s16x8 b1 = *(const s16x8*)(wb + 1 * 16 * CIN);
        const s16x8 b2 = *(const s16x8*)(wb + 2 * 16 * CIN);
        const s16x8 b3 = *(const s16x8*)(wb + 3 * 16 * CIN);
        const u32 begin = off[r * KK + k];
        const u32 end   = off[r * KK + k + 1];
        for (u32 base = begin; base < end; base += 16) {
            u32 slot = base + (u32)jrow;
            const bool valid = slot < end;
            slot = valid ? slot : end - 1;
            const u32 rc = rec[slot];
            const float* dp = df + (size_t)(rc & 0x3FFFFu) * CIN + kq * 8;
            f32x4 x0 = *(const f32x4*)dp;
            f32x4 x1 = *(const f32x4*)(dp + 4);
            if (!valid) { x0 = (f32x4){0,0,0,0}; x1 = (f32x4){0,0,0,0}; }
            s16x8 a;
            a[0]=f2bf(x0[0]); a[1]=f2bf(x0[1]); a[2]=f2bf(x0[2]); a[3]=f2bf(x0[3]);
            a[4]=f2bf(x1[0]); a[5]=f2bf(x1[1]); a[6]=f2bf(x1[2]); a[7]=f2bf(x1[3]);
            const f32x4 z = {0.f,0.f,0.f,0.f};
            const f32x4 d0 = __builtin_amdgcn_mfma_f32_16x16x32_bf16(b0, a, z, 0, 0, 0);
            const f32x4 d1 = __builtin_amdgcn_mfma_f32_16x16x32_bf16(b1, a, z, 0, 0, 0);
            const f32x4 d2 = __builtin_amdgcn_mfma_f32_16x16x32_bf16(b2, a, z, 0, 0, 0);
            const f32x4 d3 = __builtin_amdgcn_mfma_f32_16x16x32_bf16(b3, a, z, 0, 0, 0);
            const int lo = (int)((rc >> 18) & 127u);
            float* ap = acc + lo * COUT + kq * 4;
            #pragma unroll
            for (int g = 0; g < 4; ++g) {
                atomicAdd(ap + g,      d0[g]);
                atomicAdd(ap + 16 + g, d1[g]);
                atomicAdd(ap + 32 + g, d2[g]);
                atomicAdd(ap + 48 + g, d3[g]);
            }
        }
    }
    __syncthreads();
    {
        const int c = tid & 63;
        float s = 0.0f, sq = 0.0f;
        for (int row = tid >> 6; row < ROWS_PER_BIN; row += 4) {
            const float x = acc[row * COUT + c];
            s += x; sq += x * x;
        }
        sred[tid] = s; sred[256 + tid] = sq;
        __syncthreads();
        if (tid < 64) {
            atomicAdd(&stats[tid],      sred[tid] + sred[tid+64] + sred[tid+128] + sred[tid+192]);
            atomicAdd(&stats[64+tid],   sred[256+tid] + sred[320+tid] + sred[384+tid] + sred[448+tid]);
        }
    }
    const float4* a4p = (const float4*)acc;
    float4* o4 = (float4*)out;
    for (int i = tid; i < ROWS_PER_BIN * COUT / 4; i += 256)
        o4[r * (ROWS_PER_BIN * COUT / 4) + i] = a4p[i];
}

// ---------------- BN normalize (in place) ----------------
__global__ __launch_bounds__(256) void bn_norm(
    float* __restrict__ out, const float* __restrict__ stats,
    const float* __restrict__ gamma, const float* __restrict__ beta)
{
    __shared__ float scale[COUT], bias[COUT];
    if (threadIdx.x < COUT) {
        const int c = threadIdx.x;
        const float invN = 1.0f / (float)N_OUT;
        const float mean = stats[c] * invN;
        const float var  = stats[64 + c] * invN - mean * mean;
        const float inv  = rsqrtf(var + BN_EPS);
        const float g    = gamma[c];
        scale[c] = inv * g;
        bias[c]  = beta[c] - mean * inv * g;
    }
    __syncthreads();

    const int tid    = blockIdx.x * blockDim.x + threadIdx.x;
    const int stride = gridDim.x * blockDim.x;
    const int total4 = N_OUT * COUT / 4;
    float4* o4 = (float4*)out;
    for (int i = tid; i < total4; i += stride) {
        float4 v = o4[i];
        const int c0 = (i * 4) & 63;
        v.x = v.x * scale[c0 + 0] + bias[c0 + 0];
        v.y = v.y * scale[c0 + 1] + bias[c0 + 1];
        v.z = v.z * scale[c0 + 2] + bias[c0 + 2];
        v.w = v.w * scale[c0 + 3] + bias[c0 + 3];
        o4[i] = v;
    }
}

// ---------------- Fallback (round-1 path) if workspace too small ----------
__global__ __launch_bounds__(256) void conv_scatter_fb(
    const float* __restrict__ data, const float* __restrict__ W,
    const int* __restrict__ in_idx, const int* __restrict__ out_idx,
    float* __restrict__ out)
{
    __shared__ float Wlds[CIN * COUT];
    const int k   = blockIdx.x / 256;
    const int blk = blockIdx.x % 256;
    for (int i = threadIdx.x; i < CIN * COUT; i += 256)
        Wlds[i] = W[k * CIN * COUT + i];
    __syncthreads();
    const int wave = threadIdx.x >> 6;
    const int lane = threadIdx.x & 63;
    const int base = k * M_PAIRS + blk * 1024 + wave * 256;
    for (int p = 0; p < 256; ++p) {
        const int in_i  = in_idx[base + p];
        const int out_i = out_idx[base + p];
        const float val = data[in_i * CIN + (lane & 31)];
        float a = 0.0f;
        #pragma unroll
        for (int c = 0; c < CIN; ++c)
            a = fmaf(__shfl(val, c, 64), Wlds[c * COUT + lane], a);
        atomicAdd(&out[out_i * COUT + lane], a);
    }
}

__global__ __launch_bounds__(256) void bn_stats_fb(
    const float* __restrict__ out, float* __restrict__ stats)
{
    const int tid    = blockIdx.x * 256 + threadIdx.x;
    const int stride = gridDim.x * 256;
    float s = 0.0f, sq = 0.0f;
    for (int i = tid; i < N_OUT * COUT; i += stride) {
        const float x = out[i]; s += x; sq += x * x;
    }
    __shared__ float ls[256], lsq[256];
    ls[threadIdx.x] = s; lsq[threadIdx.x] = sq;
    __syncthreads();
    if (threadIdx.x < 64) {
        const int c = threadIdx.x;
        atomicAdd(&stats[c],      ls[c] + ls[c+64] + ls[c+128] + ls[c+192]);
        atomicAdd(&stats[64 + c], lsq[c] + lsq[c+64] + lsq[c+128] + lsq[c+192]);
    }
}

extern "C" void kernel_launch(void* const* d_in, const int* in_sizes, int n_in,
                              void* d_out, int out_size, void* d_ws, size_t ws_size,
                              hipStream_t stream) {
    const float* data    = (const float*)d_in[0];
    const float* W       = (const float*)d_in[1];
    const float* gamma   = (const float*)d_in[2];
    const float* beta    = (const float*)d_in[3];
    const int*   in_idx  = (const int*)d_in[4];
    const int*   out_idx = (const int*)d_in[5];
    float* out = (float*)d_out;

    // workspace layout (u32 units; every section 16B-aligned)
    u32* cnt     = (u32*)d_ws;                       // NBINS
    u32* off     = cnt + NBINS;                      // NBINS+4
    u32* rec     = off + NBINS + 4;                  // TOTAL_E + 16
    u32* partial = rec + TOTAL_E + 16;               // 128
    short* Wt    = (short*)(partial + 128);          // KK*COUT*CIN shorts
    float* stats = (float*)(Wt + KK * COUT * CIN);   // 128
    short* dataBF = (short*)(stats + 128);           // N_IN*CIN shorts (16.8 MB)

    const size_t base_needed =
        (size_t)(NBINS + NBINS + 4 + TOTAL_E + 16 + 128 + KK * COUT * CIN / 2 + 128) * 4;
    const size_t bf_needed = base_needed + (size_t)N_IN * CIN * 2;

    if (ws_size >= base_needed) {
        hipMemsetAsync(cnt, 0, (size_t)NBINS * sizeof(u32), stream);
        hipMemsetAsync(stats, 0, 128 * sizeof(float), stream);

        w_convert<<<(KK * COUT * CIN + 255) / 256, 256, 0, stream>>>(W, Wt);
        bin_count<<<2048, 256, 0, stream>>>((const int4*)out_idx, cnt);
        scan_part<<<NBINS / 1024, 1024, 0, stream>>>(cnt, partial);
        scan_small<<<1, 1, 0, stream>>>(partial);
        scan_final<<<NBINS / 1024, 1024, 0, stream>>>(cnt, off, partial);
        bin_scatter<<<2048, 256, 0, stream>>>((const int4*)in_idx, (const int4*)out_idx, cnt, rec);

        if (ws_size >= bf_needed) {
            data_convert<<<(N_IN * CIN / 8 + 255) / 256, 256, 0, stream>>>(
                (const f32x4*)data, (s16x8*)dataBF);
            range_accum<<<NR, 512, 0, stream>>>(dataBF, Wt, off, rec, out, stats);
        } else {
            range_accum_f32<<<NR, 256, 0, stream>>>(data, Wt, off, rec, out, stats);
        }
        bn_norm<<<2048, 256, 0, stream>>>(out, stats, gamma, beta);
    } else {
        float* stats_fb = (float*)d_ws;
        hipMemsetAsync(d_out, 0, (size_t)N_OUT * COUT * sizeof(float), stream);
        hipMemsetAsync(stats_fb, 0, 128 * sizeof(float), stream);
        conv_scatter_fb<<<KK * 256, 256, 0, stream>>>(data, W, in_idx, out_idx, out);
        bn_stats_fb<<<1024, 256, 0, stream>>>(out, stats_fb);
        bn_norm<<<2048, 256, 0, stream>>>(out, stats_fb, gamma, beta);
    }
}